// Round 1
// 618.708 us; speedup vs baseline: 1.0793x; 1.0793x over previous
//
#include <hip/hip_runtime.h>
#include <math.h>

// SimpleBICEPLayer fused kernel, round 4.
//
//   fb[b]          = sigmoid(x[b,:] . W_fb + b_fb)
//   endpoints[b,p] = sqrt(dt) * ( 0.5 * sum_s noise[b,p,s]
//                                + fb[b] * sum_s e[s]*noise[b,p,s] ),  e[s]=exp(-0.002 s)
//   out[b,o]       = sum_p endpoints[b,p] * W_agg[o,p] + b_agg[o]
//
// Round-4 change vs round-3: async noise staging.
//  - __builtin_amdgcn_global_load_lds width=16 replaces the global->reg->LDS
//    round trip (the LDS layout was already linear: wave-uniform base +
//    lane*16, exactly what the instruction writes).
//  - RAW s_barrier + counted "s_waitcnt vmcnt(7)" replaces __syncthreads()
//    in the chunk loop. Round-3's __syncthreads() compiled to a full
//    s_waitcnt vmcnt(0) drain per chunk, which drained the just-issued
//    prefetch and serialized every chunk on HBM latency. Now the next
//    chunk's 7 loads stay in flight across the barrier (vmcnt never 0
//    until the last chunk).
//  - All 256 threads issue 7 loads/chunk (uniform vmcnt accounting):
//    the 7th slot's out-of-range lanes read a wave-uniform duplicate of
//    row 15 (single coalesced L2-hit line) into a 3 KB LDS pad.
// Compute math, phase A, and the MFMA epilogue are unchanged from the
// verified round-3 kernel (absmax 0.03125).

#define B_TOTAL 8192
#define D_IN    512
#define D_OUT   1024
#define NP      256
#define NS      50
#define BT      16
#define THREADS 256
#define PCHUNK  8
#define NCHUNK  (NP / PCHUNK)      // 32
#define CHUNK_F4 1600              // real float4s per chunk (16 rows * 8 p * 50 s / 4)
#define CHUNK_F4P 1792             // padded to a multiple of 256 (7 slots * 256 threads)
#define ROW_F4   100               // per-row float4s per chunk (8*50/4)
#define EP_STRIDE 264              // 256 + 8 pad

#define SQRT_DT 0.14142135623730951f

typedef __bf16 bf16x8 __attribute__((ext_vector_type(8)));
typedef float  f32x4  __attribute__((ext_vector_type(4)));

__device__ __forceinline__ unsigned short f2bf(float f) {
    unsigned u = __float_as_uint(f);
    return (unsigned short)((u + 0x7FFFu + ((u >> 16) & 1u)) >> 16);
}

// global (per-lane addr) -> LDS (wave-uniform base + lane*16), async, vmcnt-tracked
__device__ __forceinline__ void async_cp16(const float4* g, float* l) {
    __builtin_amdgcn_global_load_lds(
        (const __attribute__((address_space(1))) void*)g,
        (__attribute__((address_space(3))) void*)l,
        16, 0, 0);
}

__global__ __launch_bounds__(THREADS, 2) void bicep_main(
    const float* __restrict__ x,
    const float* __restrict__ Wfb,
    const float* __restrict__ bfb,
    const float* __restrict__ Wagg,
    const float* __restrict__ bagg,
    const float* __restrict__ noise,
    float* __restrict__ out)
{
    __shared__ __align__(16) float nbuf[2][CHUNK_F4P * 4];         // 57344 B (incl. pad)
    __shared__ __align__(16) unsigned short ep_bf[BT * EP_STRIDE]; // 8448 B
    __shared__ float fb_s[BT];
    __shared__ float bagg_s[D_OUT];                                // 4096 B

    const int tid  = threadIdx.x;
    const int lane = tid & 63;
    const int wave = tid >> 6;
    const int b0   = blockIdx.x * BT;

    // ---- Phase A: bias table, feedback sigmoid for 16 rows ----
    {
        #pragma unroll
        for (int i = 0; i < D_OUT / THREADS; ++i)
            bagg_s[i * THREADS + tid] = bagg[i * THREADS + tid];

        const float bf_b = bfb[0];
        const float4* wf = (const float4*)Wfb + lane * 2;
        float4 wa = wf[0], wb = wf[1];
        #pragma unroll
        for (int rr = 0; rr < 4; ++rr) {
            int row = wave * 4 + rr;
            const float4* xr = (const float4*)(x + (size_t)(b0 + row) * D_IN) + lane * 2;
            float4 xa = xr[0], xb = xr[1];
            float p = xa.x*wa.x + xa.y*wa.y + xa.z*wa.z + xa.w*wa.w
                    + xb.x*wb.x + xb.y*wb.y + xb.z*wb.z + xb.w*wb.w;
            #pragma unroll
            for (int mm = 32; mm >= 1; mm >>= 1) p += __shfl_xor(p, mm, 64);
            if (lane == 0) fb_s[row] = 1.0f / (1.0f + __expf(-(p + bf_b)));
        }
    }

    // ---- Per-thread constants for streaming + compute ----
    const int h     = tid & 1;          // s-half (0: s<25, 1: s>=25)
    const int jpair = tid >> 1;         // 0..127 pair within chunk
    const int c_row = jpair >> 3;       // 0..15  (== tid>>4)
    const int c_pl  = jpair & 7;        // 0..7

    float ereg[25];
    #pragma unroll
    for (int s = 0; s < 25; ++s)
        ereg[s] = __expf(-0.002f * (float)(h * 25 + s));

    // Staging map: flat float4 index g4 = r*256+tid over the 25.6 KB chunk;
    // row = g4/100, off = g4%100 (chunk c adds c*100 f4 within the row).
    // Slot 6, tid>=64 (g4>=1600): clamp to a wave-uniform dup of row 15 f4 0
    // (one coalesced line, L2-hit); it lands in the LDS pad region.
    const float4* nptr[7];
    #pragma unroll
    for (int r = 0; r < 7; ++r) {
        int g4  = r * 256 + tid;
        int row = g4 / 100;
        int off = g4 - row * 100;
        if (row > BT - 1) { row = BT - 1; off = 0; }
        nptr[r] = (const float4*)(noise + (size_t)(b0 + row) * (NP * NS)) + off;
    }

    __syncthreads();   // phase A visible; vmcnt/lgkmcnt fully drained ONCE here

    // ---- Prologue: chunk 0 in flight ----
    #pragma unroll
    for (int r = 0; r < 7; ++r)
        async_cp16(nptr[r], nbuf[0] + (r * 256 + wave * 64) * 4);

    // ---- Streaming loop: double-buffered LDS, counted vmcnt, raw barriers ----
    for (int c = 0; c < NCHUNK; ++c) {
        const float* nb = nbuf[c & 1];

        if (c + 1 < NCHUNK) {
            float* nbn = nbuf[(c + 1) & 1];
            #pragma unroll
            for (int r = 0; r < 7; ++r)
                async_cp16(nptr[r] + (c + 1) * ROW_F4, nbn + (r * 256 + wave * 64) * 4);
            // wait for chunk c's 7 loads; chunk c+1's 7 remain in flight
            asm volatile("s_waitcnt vmcnt(7)" ::: "memory");
        } else {
            asm volatile("s_waitcnt vmcnt(0)" ::: "memory");
        }
        __builtin_amdgcn_s_barrier();        // all waves' chunk-c data landed
        asm volatile("" ::: "memory");

        // s-reduction: 2 threads per (row,p) pair, 25 floats each
        const float* src = &nb[c_row * (PCHUNK * NS) + c_pl * NS + h * 25];
        float s0 = 0.f, s1 = 0.f;
        #pragma unroll
        for (int s = 0; s < 25; ++s) {
            float nv = src[s];
            s0 += nv;
            s1 = fmaf(ereg[s], nv, s1);
        }
        s0 += __shfl_xor(s0, 1, 64);
        s1 += __shfl_xor(s1, 1, 64);
        if (h == 0) {
            float ep = SQRT_DT * fmaf(fb_s[c_row], s1, 0.5f * s0);
            ep_bf[c_row * EP_STRIDE + c * PCHUNK + c_pl] = f2bf(ep);
        }

        asm volatile("" ::: "memory");
        __builtin_amdgcn_s_barrier();        // reads of nb done before it is re-targeted
    }
    __syncthreads();   // drain ep_bf ds_writes before cross-wave epilogue reads

    // ---- Epilogue: out[16 x 1024] = ep(16x256) @ W^T via bf16 MFMA.
    // A-frag: lane holds A[m=lane&15][k=(lane>>4)*8+j];
    // B-frag: lane holds B[k=(lane>>4)*8+j][n=lane&15] = W[O*16+n][k];
    // C/D:    col=lane&15, row=(lane>>4)*4+reg.
    // W_agg read fp32 from global (L2-resident), converted in-register. ----
    {
        const int m  = lane & 15;
        const int kg = lane >> 4;

        bf16x8 afr[8];
        #pragma unroll
        for (int ks = 0; ks < 8; ++ks)
            afr[ks] = *(const bf16x8*)&ep_bf[m * EP_STRIDE + ks * 32 + kg * 8];

        #pragma unroll 2
        for (int i = 0; i < 16; ++i) {
            int O = wave * 16 + i;               // o-tile: cols O*16..O*16+15
            const float* wp = Wagg + (size_t)(O * 16 + m) * NP + kg * 8;
            f32x4 acc = {0.f, 0.f, 0.f, 0.f};
            #pragma unroll
            for (int ks = 0; ks < 8; ++ks) {
                float4 wa = *(const float4*)(wp + ks * 32);
                float4 wb = *(const float4*)(wp + ks * 32 + 4);
                bf16x8 bfr = { (__bf16)wa.x, (__bf16)wa.y, (__bf16)wa.z, (__bf16)wa.w,
                               (__bf16)wb.x, (__bf16)wb.y, (__bf16)wb.z, (__bf16)wb.w };
                acc = __builtin_amdgcn_mfma_f32_16x16x32_bf16(afr[ks], bfr, acc, 0, 0, 0);
            }
            float bias = bagg_s[O * 16 + m];
            #pragma unroll
            for (int r = 0; r < 4; ++r)
                out[(size_t)(b0 + kg * 4 + r) * D_OUT + O * 16 + m] = acc[r] + bias;
        }
    }
}

extern "C" void kernel_launch(void* const* d_in, const int* in_sizes, int n_in,
                              void* d_out, int out_size, void* d_ws, size_t ws_size,
                              hipStream_t stream) {
    const float* x     = (const float*)d_in[0];
    const float* Wfb   = (const float*)d_in[1];
    const float* bfb   = (const float*)d_in[2];
    const float* Wagg  = (const float*)d_in[3];
    const float* bagg  = (const float*)d_in[4];
    const float* noise = (const float*)d_in[5];
    float* out = (float*)d_out;
    (void)d_ws; (void)ws_size;

    bicep_main<<<dim3(B_TOTAL / BT), dim3(THREADS), 0, stream>>>(
        x, Wfb, bfb, Wagg, bagg, noise, out);
}

// Round 2
// 592.653 us; speedup vs baseline: 1.1268x; 1.0440x over previous
//
#include <hip/hip_runtime.h>
#include <math.h>

// SimpleBICEPLayer fused kernel, round 5.
//
//   fb[b]          = sigmoid(x[b,:] . W_fb + b_fb)
//   endpoints[b,p] = sqrt(dt) * ( 0.5 * sum_s noise[b,p,s]
//                                + fb[b] * sum_s e[s]*noise[b,p,s] ),  e[s]=exp(-0.002 s)
//   out[b,o]       = sum_p endpoints[b,p] * W_agg[o,p] + b_agg[o]
//
// Round-5 change vs round-4: INTERLEAVED epilogue.
// Round-4's epilogue ran after the streaming loop: each block read 1 MB of
// W_agg fp32 from L2 (strided) -> ~15 us of L2-bound serial tail per CU
// with HBM idle. Now the K=256 MFMA reduction is split into 8 K-groups of
// 32; after every 4th chunk (one K-group of endpoints complete) each wave
// runs its 16 MFMAs for that group, accumulating into persistent acc[16]
// registers. W_agg L2 traffic + MFMA issue hide under the HBM streaming of
// later chunks; tail = last K-group + out-write only.
// Accumulation order over K-groups is identical to round-4's ks loop ->
// bit-identical output.
//
// vmcnt note: W_agg loads are compiler-managed and issued AFTER the next
// chunk's 7 global_load_lds; compiler waits on W_agg data force those
// asyncs drained (in-order vmcnt), which the next vmcnt(7) required
// anyway -- steady-state prefetch depth (1 chunk) is preserved.

#define B_TOTAL 8192
#define D_IN    512
#define D_OUT   1024
#define NP      256
#define NS      50
#define BT      16
#define THREADS 256
#define PCHUNK  8
#define NCHUNK  (NP / PCHUNK)      // 32
#define CHUNK_F4 1600              // real float4s per chunk (16 rows * 8 p * 50 s / 4)
#define CHUNK_F4P 1792             // padded to a multiple of 256 (7 slots * 256 threads)
#define ROW_F4   100               // per-row float4s per chunk (8*50/4)
#define EP_STRIDE 264              // 256 + 8 pad

#define SQRT_DT 0.14142135623730951f

typedef __bf16 bf16x8 __attribute__((ext_vector_type(8)));
typedef float  f32x4  __attribute__((ext_vector_type(4)));

__device__ __forceinline__ unsigned short f2bf(float f) {
    unsigned u = __float_as_uint(f);
    return (unsigned short)((u + 0x7FFFu + ((u >> 16) & 1u)) >> 16);
}

// global (per-lane addr) -> LDS (wave-uniform base + lane*16), async, vmcnt-tracked
__device__ __forceinline__ void async_cp16(const float4* g, float* l) {
    __builtin_amdgcn_global_load_lds(
        (const __attribute__((address_space(1))) void*)g,
        (__attribute__((address_space(3))) void*)l,
        16, 0, 0);
}

__global__ __launch_bounds__(THREADS, 2) void bicep_main(
    const float* __restrict__ x,
    const float* __restrict__ Wfb,
    const float* __restrict__ bfb,
    const float* __restrict__ Wagg,
    const float* __restrict__ bagg,
    const float* __restrict__ noise,
    float* __restrict__ out)
{
    __shared__ __align__(16) float nbuf[2][CHUNK_F4P * 4];         // 57344 B (incl. pad)
    __shared__ __align__(16) unsigned short ep_bf[BT * EP_STRIDE]; // 8448 B
    __shared__ float fb_s[BT];
    __shared__ float bagg_s[D_OUT];                                // 4096 B

    const int tid  = threadIdx.x;
    const int lane = tid & 63;
    const int wave = tid >> 6;
    const int b0   = blockIdx.x * BT;

    // ---- Phase A: bias table, feedback sigmoid for 16 rows ----
    {
        #pragma unroll
        for (int i = 0; i < D_OUT / THREADS; ++i)
            bagg_s[i * THREADS + tid] = bagg[i * THREADS + tid];

        const float bf_b = bfb[0];
        const float4* wf = (const float4*)Wfb + lane * 2;
        float4 wa = wf[0], wb = wf[1];
        #pragma unroll
        for (int rr = 0; rr < 4; ++rr) {
            int row = wave * 4 + rr;
            const float4* xr = (const float4*)(x + (size_t)(b0 + row) * D_IN) + lane * 2;
            float4 xa = xr[0], xb = xr[1];
            float p = xa.x*wa.x + xa.y*wa.y + xa.z*wa.z + xa.w*wa.w
                    + xb.x*wb.x + xb.y*wb.y + xb.z*wb.z + xb.w*wb.w;
            #pragma unroll
            for (int mm = 32; mm >= 1; mm >>= 1) p += __shfl_xor(p, mm, 64);
            if (lane == 0) fb_s[row] = 1.0f / (1.0f + __expf(-(p + bf_b)));
        }
    }

    // ---- Per-thread constants for streaming + compute ----
    const int h     = tid & 1;          // s-half (0: s<25, 1: s>=25)
    const int jpair = tid >> 1;         // 0..127 pair within chunk
    const int c_row = jpair >> 3;       // 0..15  (== tid>>4)
    const int c_pl  = jpair & 7;        // 0..7

    float ereg[25];
    #pragma unroll
    for (int s = 0; s < 25; ++s)
        ereg[s] = __expf(-0.002f * (float)(h * 25 + s));

    // MFMA lane roles (persistent; used by interleaved epilogue)
    const int m  = lane & 15;
    const int kg = lane >> 4;
    f32x4 acc[16];
    #pragma unroll
    for (int i = 0; i < 16; ++i) acc[i] = (f32x4){0.f, 0.f, 0.f, 0.f};

    // Staging map: flat float4 index g4 = r*256+tid over the 25.6 KB chunk;
    // row = g4/100, off = g4%100 (chunk c adds c*100 f4 within the row).
    // Slot 6, tid>=64 (g4>=1600): clamp to a wave-uniform dup of row 15 f4 0
    // (one coalesced line, L2-hit); it lands in the LDS pad region.
    const float4* nptr[7];
    #pragma unroll
    for (int r = 0; r < 7; ++r) {
        int g4  = r * 256 + tid;
        int row = g4 / 100;
        int off = g4 - row * 100;
        if (row > BT - 1) { row = BT - 1; off = 0; }
        nptr[r] = (const float4*)(noise + (size_t)(b0 + row) * (NP * NS)) + off;
    }

    __syncthreads();   // phase A visible; vmcnt/lgkmcnt fully drained ONCE here

    // ---- Prologue: chunk 0 in flight ----
    #pragma unroll
    for (int r = 0; r < 7; ++r)
        async_cp16(nptr[r], nbuf[0] + (r * 256 + wave * 64) * 4);

    // ---- Streaming loop: double-buffered LDS, counted vmcnt, raw barriers,
    //      one K-group of MFMA interleaved every 4 chunks ----
    for (int c = 0; c < NCHUNK; ++c) {
        const float* nb = nbuf[c & 1];

        if (c + 1 < NCHUNK) {
            float* nbn = nbuf[(c + 1) & 1];
            #pragma unroll
            for (int r = 0; r < 7; ++r)
                async_cp16(nptr[r] + (c + 1) * ROW_F4, nbn + (r * 256 + wave * 64) * 4);
            // wait for chunk c's 7 loads; chunk c+1's 7 remain in flight
            asm volatile("s_waitcnt vmcnt(7)" ::: "memory");
        } else {
            asm volatile("s_waitcnt vmcnt(0)" ::: "memory");
        }
        __builtin_amdgcn_s_barrier();        // all waves' chunk-c data landed
        asm volatile("" ::: "memory");

        // s-reduction: 2 threads per (row,p) pair, 25 floats each
        const float* src = &nb[c_row * (PCHUNK * NS) + c_pl * NS + h * 25];
        float s0 = 0.f, s1 = 0.f;
        #pragma unroll
        for (int s = 0; s < 25; ++s) {
            float nv = src[s];
            s0 += nv;
            s1 = fmaf(ereg[s], nv, s1);
        }
        s0 += __shfl_xor(s0, 1, 64);
        s1 += __shfl_xor(s1, 1, 64);
        if (h == 0) {
            float ep = SQRT_DT * fmaf(fb_s[c_row], s1, 0.5f * s0);
            ep_bf[c_row * EP_STRIDE + c * PCHUNK + c_pl] = f2bf(ep);
        }

        // drain own ds_writes (ep_bf) so they are visible to all waves
        // after the barrier; also orders nb reads before re-targeting.
        asm volatile("s_waitcnt lgkmcnt(0)" ::: "memory");
        __builtin_amdgcn_s_barrier();
        asm volatile("" ::: "memory");

        // ---- Interleaved epilogue: one K-group (32 p-values) every 4 chunks.
        // A-frag: lane holds A[m][k'=kg*8+j] of ep k-range [g*32, g*32+32);
        // B-frag: lane holds B[k'][n=m] = W[O*16+m][g*32+k'];
        // identical accumulation order to the old ks-loop (bit-identical out).
        if ((c & 3) == 3) {
            const int g = c >> 2;
            bf16x8 afr = *(const bf16x8*)&ep_bf[m * EP_STRIDE + g * 32 + kg * 8];
            const float* wbase = Wagg + (size_t)(wave * 256 + m) * NP + g * 32 + kg * 8;
            #pragma unroll
            for (int i = 0; i < 16; ++i) {
                const float* wp = wbase + (size_t)i * 16 * NP;
                float4 wa = *(const float4*)(wp);
                float4 wb = *(const float4*)(wp + 4);
                bf16x8 bfr = { (__bf16)wa.x, (__bf16)wa.y, (__bf16)wa.z, (__bf16)wa.w,
                               (__bf16)wb.x, (__bf16)wb.y, (__bf16)wb.z, (__bf16)wb.w };
                acc[i] = __builtin_amdgcn_mfma_f32_16x16x32_bf16(afr, bfr, acc[i], 0, 0, 0);
            }
        }
    }

    // ---- Tail: bias add + out write (C/D: col=lane&15, row=(lane>>4)*4+reg) ----
    #pragma unroll
    for (int i = 0; i < 16; ++i) {
        const int O = wave * 16 + i;             // o-tile: cols O*16..O*16+15
        const float bias = bagg_s[O * 16 + m];
        #pragma unroll
        for (int r = 0; r < 4; ++r)
            out[(size_t)(b0 + kg * 4 + r) * D_OUT + O * 16 + m] = acc[i][r] + bias;
    }
}

extern "C" void kernel_launch(void* const* d_in, const int* in_sizes, int n_in,
                              void* d_out, int out_size, void* d_ws, size_t ws_size,
                              hipStream_t stream) {
    const float* x     = (const float*)d_in[0];
    const float* Wfb   = (const float*)d_in[1];
    const float* bfb   = (const float*)d_in[2];
    const float* Wagg  = (const float*)d_in[3];
    const float* bagg  = (const float*)d_in[4];
    const float* noise = (const float*)d_in[5];
    float* out = (float*)d_out;
    (void)d_ws; (void)ws_size;

    bicep_main<<<dim3(B_TOTAL / BT), dim3(THREADS), 0, stream>>>(
        x, Wfb, bfb, Wagg, bagg, noise, out);
}